// Round 1
// baseline (954.887 us; speedup 1.0000x reference)
//
#include <hip/hip_runtime.h>

#define NLEVELS 16
#define BLOCK 256

struct HashParams {
    unsigned offs[NLEVELS + 1];  // per-level table offsets (entries)
    unsigned hsize[NLEVELS];     // per-level table size (entries)
    unsigned hash_bits;          // bit l set -> hash path for level l
    unsigned pow2_bits;          // bit l set -> hsize[l] is a power of two
};

__global__ void __launch_bounds__(BLOCK)
hashenc_fwd(const float* __restrict__ xyz,
            const float* __restrict__ emb,
            float* __restrict__ out,
            HashParams p)
{
    const int tid = threadIdx.x;
    const long b = (long)blockIdx.x * BLOCK + tid;
    __shared__ float lds[BLOCK * 33];

    const float x = xyz[b * 3 + 0];
    const float y = xyz[b * 3 + 1];
    const float z = xyz[b * 3 + 2];

#pragma unroll
    for (int l = 0; l < NLEVELS; ++l) {
        // scale = exp2(l)*16 - 1, exact integer in f32
        const float scale = (float)((16u << l) - 1u);
        const float px = x * scale + 0.5f;
        const float py = y * scale + 0.5f;
        const float pz = z * scale + 0.5f;
        const float gx = floorf(px), gy = floorf(py), gz = floorf(pz);
        const float fx = px - gx, fy = py - gy, fz = pz - gz;
        const unsigned ix = (unsigned)gx, iy = (unsigned)gy, iz = (unsigned)gz;
        const unsigned hs = p.hsize[l];
        const float2* __restrict__ tab = (const float2*)emb + p.offs[l];

        unsigned idx[8];
        if ((p.hash_bits >> l) & 1u) {
            // spatial hash: x*1 ^ y*P1 ^ z*P2 (u32 wraparound)
            const unsigned hy0 = iy * 2654435761u;
            const unsigned hz0 = iz * 805459861u;
            const unsigned hy1 = hy0 + 2654435761u;
            const unsigned hz1 = hz0 + 805459861u;
            if ((p.pow2_bits >> l) & 1u) {
                const unsigned m = hs - 1u;
#pragma unroll
                for (int c = 0; c < 8; ++c)
                    idx[c] = ((ix + (c & 1)) ^ ((c & 2) ? hy1 : hy0) ^ ((c & 4) ? hz1 : hz0)) & m;
            } else {
#pragma unroll
                for (int c = 0; c < 8; ++c)
                    idx[c] = ((ix + (c & 1)) ^ ((c & 2) ? hy1 : hy0) ^ ((c & 4) ? hz1 : hz0)) % hs;
            }
        } else {
            // dense path (reference still applies % hs afterwards)
            const unsigned stride = (16u << l) + 1u;
#pragma unroll
            for (int c = 0; c < 8; ++c) {
                const unsigned lin = (ix + (c & 1))
                                   + (iy + ((c >> 1) & 1)) * stride
                                   + (iz + ((c >> 2) & 1)) * stride * stride;
                idx[c] = lin % hs;
            }
        }

        // issue all 8 gathers back-to-back for vmcnt overlap
        float2 e[8];
#pragma unroll
        for (int c = 0; c < 8; ++c) e[c] = tab[idx[c]];

        const float wx[2] = {1.0f - fx, fx};
        const float wy[2] = {1.0f - fy, fy};
        const float wz[2] = {1.0f - fz, fz};
        float o0 = 0.0f, o1 = 0.0f;
#pragma unroll
        for (int c = 0; c < 8; ++c) {
            const float w = wx[c & 1] * wy[(c >> 1) & 1] * wz[(c >> 2) & 1];
            o0 = fmaf(w, e[c].x, o0);
            o1 = fmaf(w, e[c].y, o1);
        }
        // stage per-level result; stride-33 rows -> conflict-free
        lds[tid * 33 + l * 2 + 0] = o0;
        lds[tid * 33 + l * 2 + 1] = o1;
    }

    __syncthreads();
    // block's output chunk is contiguous: 256 points x 32 feats = 32 KiB
    float* __restrict__ ochunk = out + (long)blockIdx.x * (BLOCK * 32);
#pragma unroll
    for (int k = 0; k < 32; ++k) {
        const int flat = k * BLOCK + tid;               // coalesced global index
        const float v = lds[(flat >> 5) * 33 + (flat & 31)];
        __builtin_nontemporal_store(v, ochunk + flat);  // don't pollute L2 with output
    }
}

extern "C" void kernel_launch(void* const* d_in, const int* in_sizes, int n_in,
                              void* d_out, int out_size, void* d_ws, size_t ws_size,
                              hipStream_t stream) {
    const float* xyz = (const float*)d_in[0];
    const float* emb = (const float*)d_in[1];
    float* out = (float*)d_out;
    const int B = in_sizes[0] / 3;

    // Reproduce HashEncoder.__init__ offset arithmetic exactly (host-side, cheap).
    HashParams p;
    p.offs[0] = 0;
    unsigned hash_bits = 0, pow2_bits = 0;
    long off = 0;
    for (int i = 0; i < NLEVELS; ++i) {
        const long res = 16L << i;                       // ceil(16 * 2^i)
        const long dense = (res + 1) * (res + 1) * (res + 1);
        long t = dense < (1L << 19) ? dense : (1L << 19);
        t = (t / 8) * 8;                                 // int(p/8)*8
        p.hsize[i] = (unsigned)t;
        off += t;
        p.offs[i + 1] = (unsigned)off;
        if (dense > t) hash_bits |= (1u << i);           // use_hash
        if ((t & (t - 1)) == 0) pow2_bits |= (1u << i);
    }
    p.hash_bits = hash_bits;
    p.pow2_bits = pow2_bits;

    hashenc_fwd<<<dim3(B / BLOCK), dim3(BLOCK), 0, stream>>>(xyz, emb, out, p);
}

// Round 2
// 592.544 us; speedup vs baseline: 1.6115x; 1.6115x over previous
//
#include <hip/hip_runtime.h>

#define NLEVELS 16
#define BLOCK 256
#define PPT 2  // points per thread in pass 1

struct HashParams {
    unsigned offs[NLEVELS + 1];  // per-level table offsets (entries)
    unsigned hsize[NLEVELS];     // per-level table size (entries)
    unsigned hash_bits;          // bit l set -> hash path for level l
    unsigned pow2_bits;          // bit l set -> hsize[l] is a power of two
};

// ---------------- pass 1: level-phased gather+interp -> level-major ws ------
// blockIdx = level * bpl + chunk (level-major dispatch order => each XCD's L2
// only holds ~one 4 MiB level table at a time instead of the 57 MB total).
__global__ void __launch_bounds__(BLOCK)
hashenc_pass1(const float* __restrict__ xyz,
              const float* __restrict__ emb,
              float2* __restrict__ ws,
              HashParams p, int np, int bpl_shift)
{
    const int l = blockIdx.x >> bpl_shift;
    const int chunk = blockIdx.x & ((1 << bpl_shift) - 1);
    const int tid = threadIdx.x;

    const unsigned hs = p.hsize[l];
    const float2* __restrict__ tab = (const float2*)emb + p.offs[l];
    const float scale = (float)((16u << l) - 1u);
    const bool do_hash = (p.hash_bits >> l) & 1u;
    const bool is_pow2 = (p.pow2_bits >> l) & 1u;
    float2* __restrict__ wl = ws + (size_t)l * np;

    const int base = chunk * (BLOCK * PPT) + tid;

#pragma unroll
    for (int s = 0; s < PPT; ++s) {
        const int pidx = base + s * BLOCK;
        const float x = xyz[pidx * 3 + 0];
        const float y = xyz[pidx * 3 + 1];
        const float z = xyz[pidx * 3 + 2];

        const float px = x * scale + 0.5f;
        const float py = y * scale + 0.5f;
        const float pz = z * scale + 0.5f;
        const float gx = floorf(px), gy = floorf(py), gz = floorf(pz);
        const float fx = px - gx, fy = py - gy, fz = pz - gz;
        const unsigned ix = (unsigned)gx, iy = (unsigned)gy, iz = (unsigned)gz;

        unsigned idx[8];
        if (do_hash) {
            const unsigned hy0 = iy * 2654435761u;
            const unsigned hz0 = iz * 805459861u;
            const unsigned hy1 = hy0 + 2654435761u;
            const unsigned hz1 = hz0 + 805459861u;
            if (is_pow2) {
                const unsigned m = hs - 1u;
#pragma unroll
                for (int c = 0; c < 8; ++c)
                    idx[c] = ((ix + (c & 1)) ^ ((c & 2) ? hy1 : hy0) ^ ((c & 4) ? hz1 : hz0)) & m;
            } else {
#pragma unroll
                for (int c = 0; c < 8; ++c)
                    idx[c] = ((ix + (c & 1)) ^ ((c & 2) ? hy1 : hy0) ^ ((c & 4) ? hz1 : hz0)) % hs;
            }
        } else {
            const unsigned stride = (16u << l) + 1u;
#pragma unroll
            for (int c = 0; c < 8; ++c) {
                const unsigned lin = (ix + (c & 1))
                                   + (iy + ((c >> 1) & 1)) * stride
                                   + (iz + ((c >> 2) & 1)) * stride * stride;
                idx[c] = lin % hs;
            }
        }

        float2 e[8];
#pragma unroll
        for (int c = 0; c < 8; ++c) e[c] = tab[idx[c]];

        const float wx[2] = {1.0f - fx, fx};
        const float wy[2] = {1.0f - fy, fy};
        const float wz[2] = {1.0f - fz, fz};
        float o0 = 0.0f, o1 = 0.0f;
#pragma unroll
        for (int c = 0; c < 8; ++c) {
            const float w = wx[c & 1] * wy[(c >> 1) & 1] * wz[(c >> 2) & 1];
            o0 = fmaf(w, e[c].x, o0);
            o1 = fmaf(w, e[c].y, o1);
        }
        wl[pidx] = make_float2(o0, o1);  // coalesced 8B stores, stays in L2/L3 for pass 2
    }
}

// ---------------- pass 2: transpose ws[l][p][2] -> out[p][32] ---------------
__global__ void __launch_bounds__(BLOCK)
hashenc_pass2(const float2* __restrict__ ws, float* __restrict__ out, int np)
{
    __shared__ float lds[BLOCK * 33];
    const int tid = threadIdx.x;
    const int p0 = blockIdx.x * BLOCK;

#pragma unroll
    for (int l = 0; l < NLEVELS; ++l) {
        const float2 v = ws[(size_t)l * np + p0 + tid];  // coalesced per level
        lds[tid * 33 + 2 * l + 0] = v.x;                 // bank = (tid + 2l) % 32: conflict-free
        lds[tid * 33 + 2 * l + 1] = v.y;
    }
    __syncthreads();
    float* __restrict__ ochunk = out + (size_t)blockIdx.x * (BLOCK * 32);
#pragma unroll
    for (int k = 0; k < 32; ++k) {
        const int flat = k * BLOCK + tid;
        const float v = lds[(flat >> 5) * 33 + (flat & 31)];
        __builtin_nontemporal_store(v, ochunk + flat);
    }
}

// ---------------- fallback: R1 single-pass kernel (used if ws too small) ----
__global__ void __launch_bounds__(BLOCK)
hashenc_fwd(const float* __restrict__ xyz,
            const float* __restrict__ emb,
            float* __restrict__ out,
            HashParams p)
{
    const int tid = threadIdx.x;
    const long b = (long)blockIdx.x * BLOCK + tid;
    __shared__ float lds[BLOCK * 33];

    const float x = xyz[b * 3 + 0];
    const float y = xyz[b * 3 + 1];
    const float z = xyz[b * 3 + 2];

#pragma unroll
    for (int l = 0; l < NLEVELS; ++l) {
        const float scale = (float)((16u << l) - 1u);
        const float px = x * scale + 0.5f;
        const float py = y * scale + 0.5f;
        const float pz = z * scale + 0.5f;
        const float gx = floorf(px), gy = floorf(py), gz = floorf(pz);
        const float fx = px - gx, fy = py - gy, fz = pz - gz;
        const unsigned ix = (unsigned)gx, iy = (unsigned)gy, iz = (unsigned)gz;
        const unsigned hs = p.hsize[l];
        const float2* __restrict__ tab = (const float2*)emb + p.offs[l];

        unsigned idx[8];
        if ((p.hash_bits >> l) & 1u) {
            const unsigned hy0 = iy * 2654435761u;
            const unsigned hz0 = iz * 805459861u;
            const unsigned hy1 = hy0 + 2654435761u;
            const unsigned hz1 = hz0 + 805459861u;
            if ((p.pow2_bits >> l) & 1u) {
                const unsigned m = hs - 1u;
#pragma unroll
                for (int c = 0; c < 8; ++c)
                    idx[c] = ((ix + (c & 1)) ^ ((c & 2) ? hy1 : hy0) ^ ((c & 4) ? hz1 : hz0)) & m;
            } else {
#pragma unroll
                for (int c = 0; c < 8; ++c)
                    idx[c] = ((ix + (c & 1)) ^ ((c & 2) ? hy1 : hy0) ^ ((c & 4) ? hz1 : hz0)) % hs;
            }
        } else {
            const unsigned stride = (16u << l) + 1u;
#pragma unroll
            for (int c = 0; c < 8; ++c) {
                const unsigned lin = (ix + (c & 1))
                                   + (iy + ((c >> 1) & 1)) * stride
                                   + (iz + ((c >> 2) & 1)) * stride * stride;
                idx[c] = lin % hs;
            }
        }

        float2 e[8];
#pragma unroll
        for (int c = 0; c < 8; ++c) e[c] = tab[idx[c]];

        const float wx[2] = {1.0f - fx, fx};
        const float wy[2] = {1.0f - fy, fy};
        const float wz[2] = {1.0f - fz, fz};
        float o0 = 0.0f, o1 = 0.0f;
#pragma unroll
        for (int c = 0; c < 8; ++c) {
            const float w = wx[c & 1] * wy[(c >> 1) & 1] * wz[(c >> 2) & 1];
            o0 = fmaf(w, e[c].x, o0);
            o1 = fmaf(w, e[c].y, o1);
        }
        lds[tid * 33 + l * 2 + 0] = o0;
        lds[tid * 33 + l * 2 + 1] = o1;
    }

    __syncthreads();
    float* __restrict__ ochunk = out + (long)blockIdx.x * (BLOCK * 32);
#pragma unroll
    for (int k = 0; k < 32; ++k) {
        const int flat = k * BLOCK + tid;
        const float v = lds[(flat >> 5) * 33 + (flat & 31)];
        __builtin_nontemporal_store(v, ochunk + flat);
    }
}

extern "C" void kernel_launch(void* const* d_in, const int* in_sizes, int n_in,
                              void* d_out, int out_size, void* d_ws, size_t ws_size,
                              hipStream_t stream) {
    const float* xyz = (const float*)d_in[0];
    const float* emb = (const float*)d_in[1];
    float* out = (float*)d_out;
    const int B = in_sizes[0] / 3;

    // Reproduce HashEncoder.__init__ offset arithmetic exactly.
    HashParams p;
    p.offs[0] = 0;
    unsigned hash_bits = 0, pow2_bits = 0;
    long off = 0;
    for (int i = 0; i < NLEVELS; ++i) {
        const long res = 16L << i;
        const long dense = (res + 1) * (res + 1) * (res + 1);
        long t = dense < (1L << 19) ? dense : (1L << 19);
        t = (t / 8) * 8;
        p.hsize[i] = (unsigned)t;
        off += t;
        p.offs[i + 1] = (unsigned)off;
        if (dense > t) hash_bits |= (1u << i);
        if ((t & (t - 1)) == 0) pow2_bits |= (1u << i);
    }
    p.hash_bits = hash_bits;
    p.pow2_bits = pow2_bits;

    const size_t need = (size_t)B * NLEVELS * sizeof(float2);
    if (ws_size >= need && (B % (BLOCK * PPT)) == 0 && (B % BLOCK) == 0) {
        int bpl_shift = 0;
        while ((1 << bpl_shift) * (BLOCK * PPT) < B) ++bpl_shift;  // B is a power of two
        const int bpl = 1 << bpl_shift;
        hashenc_pass1<<<dim3(NLEVELS * bpl), dim3(BLOCK), 0, stream>>>(
            xyz, emb, (float2*)d_ws, p, B, bpl_shift);
        hashenc_pass2<<<dim3(B / BLOCK), dim3(BLOCK), 0, stream>>>(
            (const float2*)d_ws, out, B);
    } else {
        hashenc_fwd<<<dim3(B / BLOCK), dim3(BLOCK), 0, stream>>>(xyz, emb, out, p);
    }
}